// Round 3
// baseline (349.348 us; speedup 1.0000x reference)
//
#include <hip/hip_runtime.h>
#include <math.h>

// Problem constants
#define H_GRID 32
#define W_GRID 64
#define NTOK   2048
#define NHEADS 8
#define HD     24
#define DIMC   192
#define BATCH  4

#define NBLK   1024u

static constexpr float SCALE = 0.20412414523193154f; // 1/sqrt(24)

typedef unsigned short ushort;
typedef unsigned int   uint;
typedef __attribute__((ext_vector_type(8))) _Float16 f16x8;
typedef __attribute__((ext_vector_type(4))) float    f32x4;

static __device__ __forceinline__ float4 ld4(const float* p) { return *(const float4*)p; }

static __device__ __forceinline__ ushort f2h(float f) {
    _Float16 h = (_Float16)f;
    union { _Float16 h; ushort u; } c; c.h = h; return c.u;
}
static __device__ __forceinline__ float h2f(ushort u) {
    union { ushort u; _Float16 h; } c; c.u = u; return (float)c.h;
}
static __device__ __forceinline__ f16x8 cvt8(float4 a, float4 b) {
    f16x8 r;
    r[0] = (_Float16)a.x; r[1] = (_Float16)a.y; r[2] = (_Float16)a.z; r[3] = (_Float16)a.w;
    r[4] = (_Float16)b.x; r[5] = (_Float16)b.y; r[6] = (_Float16)b.z; r[7] = (_Float16)b.w;
    return r;
}

// Device-scope software barrier (non-cooperative). Safe because residency is
// FORCED: VGPR<=128 via __launch_bounds__(256,4) => >=4 blocks/CU capacity,
// LDS padded to 40KB => <=4 blocks/CU, grid == 1024 == 256 CU * 4. Bounded
// spin so a dispatch pathology yields a wrong answer, not a hung container.
static __device__ __forceinline__ void gbar(uint* cnt) {
    __syncthreads();
    if (threadIdx.x == 0) {
        __threadfence();                      // release: flush this XCD's L2
        atomicAdd(cnt, 1u);                   // device-scope (m20)
        int spins = 0;
        while (__hip_atomic_load(cnt, __ATOMIC_RELAXED, __HIP_MEMORY_SCOPE_AGENT) < NBLK) {
            __builtin_amdgcn_s_sleep(8);
            if (++spins > 50000000) break;    // deadlock escape hatch
        }
        __threadfence();                      // acquire: invalidate stale L1/L2
    }
    __syncthreads();
}

// ---------------------------------------------------------------------------
// Single fused kernel, plain launch: 1024 blocks x 256 threads, exactly
// 4 blocks/CU. Phase 0: QKV GEMM (inline fp32->fp16 cast). Phase 1: MFMA
// local attention. Phase 2: proj GEMM. Phases separated by gbar().
// Phase bodies byte-identical to the verified R2 kernels.
// ---------------------------------------------------------------------------
__global__ __launch_bounds__(256, 4) void fused(const float* __restrict__ x,
                                                const float* __restrict__ qkv_w,
                                                const float* __restrict__ qkv_b,
                                                const float* __restrict__ proj_w,
                                                const float* __restrict__ proj_b,
                                                ushort* __restrict__ Qh,
                                                ushort* __restrict__ Kh,
                                                ushort* __restrict__ VTh,
                                                ushort* __restrict__ awsh,
                                                float* __restrict__ out,
                                                uint* __restrict__ bar) {
    union SMem {
        ushort Ws[64 * 200];                 // GEMM W stage / 64x68 transpose buf
        struct {
            ushort P[32 * 328];
            ushort Os[32 * 28];
            float  mxbuf[64];
            float  sumbuf[64];
        } a;
        char force_lds[40960];               // pin LDS to 40KB -> 4 blocks/CU
    };
    __shared__ SMem sm;

    const int blkid = blockIdx.x;
    const int t     = threadIdx.x;
    const int wave  = t >> 6, lane = t & 63;
    const int n16   = lane & 15;
    const int kq    = lane >> 4;

    // ================= Phase 0: QKV GEMM with inline cast ==================
    for (int vt = blkid; vt < 1152; vt += 1024) {
        const int bx = vt & 127;
        const int by = vt >> 7;
        const int j0 = by * 64;
        const int m0 = bx * 64 + wave * 16;

        __syncthreads();                     // Ws reuse across virtual tiles

        for (int i = t; i < 1536; i += 256) {
            const int r = i / 24, c = i - (i / 24) * 24;
            const float* wsrc = &qkv_w[(size_t)(j0 + r) * 192 + c * 8];
            const float4 w0 = ld4(wsrc), w1 = ld4(wsrc + 4);
            *(ushort4*)&sm.Ws[r * 200 + c * 8] =
                make_ushort4(f2h(w0.x), f2h(w0.y), f2h(w0.z), f2h(w0.w));
            *(ushort4*)&sm.Ws[r * 200 + c * 8 + 4] =
                make_ushort4(f2h(w1.x), f2h(w1.y), f2h(w1.z), f2h(w1.w));
        }

        if (by == 0) {                       // zero Q/K d-pads for these 64 tokens
            for (int i = t; i < 1024; i += 256) {
                const int tok = bx * 64 + (i >> 4);
                const int h_  = (i >> 1) & 7;
                ushort* dst = (i & 1) ? Kh : Qh;
                const uint4 z = {0u, 0u, 0u, 0u};
                *(uint4*)&dst[((size_t)((tok >> 11) * 8 + h_) * 2048 + (tok & 2047)) * 32 + 24] = z;
            }
        }

        const float* ap = x + (size_t)(m0 + n16) * 192 + kq * 8;
        f16x8 af[6];
#pragma unroll
        for (int ks = 0; ks < 6; ks++) {
            const float4 a0 = ld4(ap + ks * 32);
            const float4 a1 = ld4(ap + ks * 32 + 4);
            af[ks] = cvt8(a0, a1);
        }

        f32x4 acc[4] = {f32x4{0,0,0,0}, f32x4{0,0,0,0}, f32x4{0,0,0,0}, f32x4{0,0,0,0}};

        __syncthreads();

#pragma unroll
        for (int ks = 0; ks < 6; ks++) {
#pragma unroll
            for (int nt = 0; nt < 4; nt++) {
                const f16x8 bf = *(const f16x8*)&sm.Ws[(nt * 16 + n16) * 200 + kq * 8 + ks * 32];
                acc[nt] = __builtin_amdgcn_mfma_f32_16x16x32_f16(af[ks], bf, acc[nt], 0, 0, 0);
            }
        }

        const int band  = by / 3;            // 0=Q, 1=K, 2=V
        const int mrow0 = m0 + kq * 4;
        const int b_    = mrow0 >> 11;
        const int tok0  = mrow0 & 2047;

        if (band == 2) {                     // V -> VT[bh][d][2080]+8, direct
#pragma unroll
            for (int nt = 0; nt < 4; nt++) {
                const int col = j0 + nt * 16 + n16;
                const int lc  = col - 384;
                const int h_  = lc / 24;
                const int d_  = lc - h_ * 24;
                const float bv = qkv_b[col];
                ushort vv[4];
#pragma unroll
                for (int r = 0; r < 4; r++) vv[r] = f2h(acc[nt][r] + bv);
                const size_t addr = ((size_t)(b_ * 8 + h_) * 32 + d_) * 2080 + 8 + tok0;
                *(ushort4*)&VTh[addr] = make_ushort4(vv[0], vv[1], vv[2], vv[3]);
            }
        } else {                             // Q/K -> LDS transpose -> coalesced
            const float sc_ = band ? 1.0f : SCALE;
            __syncthreads();                 // W reads done; reuse Ws
#pragma unroll
            for (int nt = 0; nt < 4; nt++) {
                const int col = j0 + nt * 16 + n16;
                const float bv = qkv_b[col];
#pragma unroll
                for (int r = 0; r < 4; r++) {
                    sm.Ws[(wave * 16 + kq * 4 + r) * 68 + nt * 16 + n16] =
                        f2h((acc[nt][r] + bv) * sc_);
                }
            }
            __syncthreads();
            ushort* dst = band ? Kh : Qh;
            const int lc0 = j0 - band * 192; // 0, 64, or 128
#pragma unroll
            for (int it = 0; it < 4; it++) {
                const int item = t + 256 * it;   // 0..1023
                const int tokl = item >> 4;
                const int cg   = item & 15;
                const ushort4 v = *(const ushort4*)&sm.Ws[tokl * 68 + cg * 4];
                const int lc = lc0 + cg * 4;
                const int h_ = lc / 24;
                const int d0 = lc - h_ * 24;
                const int m  = bx * 64 + tokl;
                const size_t addr = ((size_t)((m >> 11) * 8 + h_) * 2048 + (m & 2047)) * 32 + d0;
                *(ushort4*)&dst[addr] = v;
            }
        }
    }

    gbar(&bar[0]);

    // ================= Phase 1: MFMA local attention =======================
    {
        ushort* P      = sm.a.P;
        ushort* Os     = sm.a.Os;
        float*  mxbuf  = sm.a.mxbuf;
        float*  sumbuf = sm.a.sumbuf;
        const int w    = wave;
        const int quad = kq;

        for (int vb = blkid; vb < 2048; vb += 1024) {
            __syncthreads();                 // LDS reuse across virtual blocks

            const int head  = vb & 7;        // -> XCD (vb % 8 round-robin)
            const int qtile = (vb >> 3) & 63;
            const int b     = vb >> 9;
            const int qh0   = (qtile >> 3) * 4;
            const int qw0   = (qtile & 7) * 8;
            const int kw0a  = qw0 - 8;
            const int bh    = b * 8 + head;

            const ushort* Qb = Qh + (size_t)bh * 65536;
            const ushort* Kb = Kh + (size_t)bh * 65536;

            const int mt = w >> 1, nth = w & 1;
            const int mrow = 16 * mt + n16;
            const int tq_a = ((qh0 + (mrow >> 3)) << 6) + qw0 + (mrow & 7);
            const f16x8 qf = *(const f16x8*)&Qb[(size_t)tq_a * 32 + quad * 8];

            float sv[10][4];
            float mx4[4] = {-3e38f, -3e38f, -3e38f, -3e38f};
#pragma unroll
            for (int half = 0; half < 2; half++) {
                f16x8 kf[5];
                int khvv[5], kwvv[5];
#pragma unroll
                for (int jj = 0; jj < 5; jj++) {   // 5 gathers in flight
                    const int j = half * 5 + jj;
                    const int slot = (nth * 10 + j) * 16 + n16;
                    const int rr = slot >> 5, cc = slot & 31;
                    khvv[jj] = qh0 - 3 + rr;
                    kwvv[jj] = kw0a + cc;
                    const int tok = (min(max(khvv[jj], 0), 31) << 6) + min(max(kwvv[jj], 0), 63);
                    kf[jj] = *(const f16x8*)&Kb[(size_t)tok * 32 + quad * 8];
                }
#pragma unroll
                for (int jj = 0; jj < 5; jj++) {
                    const int j = half * 5 + jj;
                    f32x4 a = f32x4{0, 0, 0, 0};
                    a = __builtin_amdgcn_mfma_f32_16x16x32_f16(qf, kf[jj], a, 0, 0, 0);
                    const int khv = khvv[jj], kwv = kwvv[jj];
                    const bool kok = (khv >= 0) && (khv < 32) && (kwv >= 0) && (kwv < 64);
#pragma unroll
                    for (int r = 0; r < 4; r++) {
                        const int m   = 16 * mt + quad * 4 + r;
                        const int qhv = qh0 + (m >> 3);
                        const int qwv = qw0 + (m & 7);
                        const bool valid = kok && (abs(khv - qhv) <= 3) && (abs(kwv - qwv) <= 5);
                        const float s = valid ? a[r] : -3e38f;
                        sv[j][r] = s;
                        mx4[r] = fmaxf(mx4[r], s);
                    }
                }
            }
#pragma unroll
            for (int d = 1; d < 16; d <<= 1)
#pragma unroll
                for (int r = 0; r < 4; r++) mx4[r] = fmaxf(mx4[r], __shfl_xor(mx4[r], d));
            if (n16 == 0) {
#pragma unroll
                for (int r = 0; r < 4; r++) mxbuf[w * 16 + quad * 4 + r] = mx4[r];
            }
            __syncthreads();
#pragma unroll
            for (int r = 0; r < 4; r++) mx4[r] = fmaxf(mx4[r], mxbuf[(w ^ 1) * 16 + quad * 4 + r]);

            float sum4[4] = {0.f, 0.f, 0.f, 0.f};
#pragma unroll
            for (int j = 0; j < 10; j++) {
                const int slot = (nth * 10 + j) * 16 + n16;
#pragma unroll
                for (int r = 0; r < 4; r++) {
                    const float p = __expf(sv[j][r] - mx4[r]);
                    const ushort ph = f2h(p);
                    sum4[r] += h2f(ph);
                    P[(16 * mt + quad * 4 + r) * 328 + slot] = ph;
                }
            }
#pragma unroll
            for (int d = 1; d < 16; d <<= 1)
#pragma unroll
                for (int r = 0; r < 4; r++) sum4[r] += __shfl_xor(sum4[r], d);
            if (n16 == 0) {
#pragma unroll
                for (int r = 0; r < 4; r++) sumbuf[w * 16 + quad * 4 + r] = sum4[r];
            }
            __syncthreads();

            // ---- PV: VT gathers hoisted in batches of 5 ----
            const int mtP = w >> 1, ntP = w & 1;
            const int dcol = 16 * ntP + n16;
            const ushort* VTb = VTh + (size_t)bh * 66560;    // 32*2080
            f32x4 acc = f32x4{0, 0, 0, 0};
#pragma unroll
            for (int half = 0; half < 2; half++) {
                f16x8 vf[5], pa[5];
#pragma unroll
                for (int kk = 0; kk < 5; kk++) {
                    const int ks = half * 5 + kk;
                    const int kh_cl = min(max(qh0 - 3 + ks, 0), 31);
                    vf[kk] = *(const f16x8*)&VTb[(size_t)dcol * 2080 + 8 + (kh_cl << 6) + kw0a + quad * 8];
                    pa[kk] = *(const f16x8*)&P[(16 * mtP + n16) * 328 + ks * 32 + quad * 8];
                }
#pragma unroll
                for (int kk = 0; kk < 5; kk++) {
                    acc = __builtin_amdgcn_mfma_f32_16x16x32_f16(pa[kk], vf[kk], acc, 0, 0, 0);
                }
            }
            if (dcol < 24) {
#pragma unroll
                for (int r = 0; r < 4; r++) {
                    const int m = 16 * mtP + quad * 4 + r;
                    const float tot = sumbuf[(2 * mtP) * 16 + (m & 15)] +
                                      sumbuf[(2 * mtP + 1) * 16 + (m & 15)];
                    Os[m * 28 + dcol] = f2h(acc[r] / tot);
                }
            }
            __syncthreads();

            // ---- coalesced output: 32 tokens x 24 dims ----
            if (t < 192) {
                const int tok = t / 6, g = t - (t / 6) * 6;
                const ushort4 v = *(const ushort4*)&Os[tok * 28 + g * 4];
                const int tq = ((qh0 + (tok >> 3)) << 6) + qw0 + (tok & 7);
                *(ushort4*)&awsh[((size_t)(b * 2048 + tq)) * 192 + head * 24 + g * 4] = v;
            }
        }
    }

    gbar(&bar[16]);

    // ================= Phase 2: proj GEMM (inline W cast) ==================
    if (blkid < 384) {
        const int bx = blkid & 127;
        const int by = blkid >> 7;
        const int j0 = by * 64;
        const int m0 = bx * 64 + wave * 16;

        for (int i = t; i < 1536; i += 256) {
            const int r = i / 24, c = i - (i / 24) * 24;
            const float* wsrc = &proj_w[(size_t)(j0 + r) * 192 + c * 8];
            const float4 w0 = ld4(wsrc), w1 = ld4(wsrc + 4);
            *(ushort4*)&sm.Ws[r * 200 + c * 8] =
                make_ushort4(f2h(w0.x), f2h(w0.y), f2h(w0.z), f2h(w0.w));
            *(ushort4*)&sm.Ws[r * 200 + c * 8 + 4] =
                make_ushort4(f2h(w1.x), f2h(w1.y), f2h(w1.z), f2h(w1.w));
        }

        const ushort* ap = awsh + (size_t)(m0 + n16) * 192 + kq * 8;

        f16x8 af[6];
#pragma unroll
        for (int ks = 0; ks < 6; ks++) af[ks] = *(const f16x8*)(ap + ks * 32);

        f32x4 acc[4] = {f32x4{0,0,0,0}, f32x4{0,0,0,0}, f32x4{0,0,0,0}, f32x4{0,0,0,0}};

        __syncthreads();

#pragma unroll
        for (int ks = 0; ks < 6; ks++) {
#pragma unroll
            for (int nt = 0; nt < 4; nt++) {
                const f16x8 bf = *(const f16x8*)&sm.Ws[(nt * 16 + n16) * 200 + kq * 8 + ks * 32];
                acc[nt] = __builtin_amdgcn_mfma_f32_16x16x32_f16(af[ks], bf, acc[nt], 0, 0, 0);
            }
        }

#pragma unroll
        for (int nt = 0; nt < 4; nt++) {
            const int col = j0 + nt * 16 + n16;
            const float bv = proj_b[col];
#pragma unroll
            for (int r = 0; r < 4; r++) {
                const int m = m0 + kq * 4 + r;
                out[(size_t)m * 192 + col] = acc[nt][r] + bv;
            }
        }
    }
}

// ---------------------------------------------------------------------------
// Launch: memset barrier counters (capture-safe), then one plain launch of
// the fused kernel: 1024 blocks x 256 threads.
// ---------------------------------------------------------------------------
extern "C" void kernel_launch(void* const* d_in, const int* in_sizes, int n_in,
                              void* d_out, int out_size, void* d_ws, size_t ws_size,
                              hipStream_t stream) {
    const float* x      = (const float*)d_in[0];
    const float* qkv_w  = (const float*)d_in[1];
    const float* qkv_b  = (const float*)d_in[2];
    const float* proj_w = (const float*)d_in[3];
    const float* proj_b = (const float*)d_in[4];
    // d_in[5] mask: fixed 7x11 window, recomputed analytically; unused.

    char* wsb = (char*)d_ws;
    ushort* Qh   = (ushort*)(wsb + 0);          // [32,2048,32] fp16
    ushort* Kh   = (ushort*)(wsb + 4194304);    // [32,2048,32]
    ushort* VTh  = (ushort*)(wsb + 8388608);    // [32,32,2080]
    ushort* awsh = (ushort*)(wsb + 12648448);   // [8192,192]
    uint*   bar  = (uint*)(wsb + 16777216);     // barrier counters (zeroed below)
    float*  out  = (float*)d_out;

    hipMemsetAsync(bar, 0, 128, stream);        // ws is POISONED each iter; re-zero
    hipLaunchKernelGGL(fused, dim3(1024), dim3(256), 0, stream,
                       x, qkv_w, qkv_b, proj_w, proj_b, Qh, Kh, VTh, awsh, out, bar);
}

// Round 4
// 246.466 us; speedup vs baseline: 1.4174x; 1.4174x over previous
//
#include <hip/hip_runtime.h>
#include <math.h>

// Problem constants
#define H_GRID 32
#define W_GRID 64
#define NTOK   2048
#define NHEADS 8
#define HD     24
#define DIMC   192
#define BATCH  4

// DIAGNOSTIC: repeat each kernel body REP times (idempotent) so every kernel
// exceeds the ~43us harness fill dispatches and surfaces in the rocprof top-5
// with per-kernel counters. Pointer laundering prevents load hoisting.
#define REP 6

static constexpr float SCALE = 0.20412414523193154f; // 1/sqrt(24)

typedef unsigned short ushort;
typedef unsigned int   uint;
typedef __attribute__((ext_vector_type(8))) _Float16 f16x8;
typedef __attribute__((ext_vector_type(4))) float    f32x4;

static __device__ __forceinline__ float4 ld4(const float* p) { return *(const float4*)p; }

static __device__ __forceinline__ ushort f2h(float f) {
    _Float16 h = (_Float16)f;
    union { _Float16 h; ushort u; } c; c.h = h; return c.u;
}
static __device__ __forceinline__ float h2f(ushort u) {
    union { ushort u; _Float16 h; } c; c.u = u; return (float)c.h;
}
static __device__ __forceinline__ f16x8 cvt8(float4 a, float4 b) {
    f16x8 r;
    r[0] = (_Float16)a.x; r[1] = (_Float16)a.y; r[2] = (_Float16)a.z; r[3] = (_Float16)a.w;
    r[4] = (_Float16)b.x; r[5] = (_Float16)b.y; r[6] = (_Float16)b.z; r[7] = (_Float16)b.w;
    return r;
}

// ---------------------------------------------------------------------------
// QKV GEMM (fp16 MFMA) with inline fp32->fp16 cast. REP'd for diagnosis.
// ---------------------------------------------------------------------------
__global__ __launch_bounds__(256, 4) void gemm_qkv(const float* __restrict__ x,
                                                   const float* __restrict__ Wf,
                                                   const float* __restrict__ bias,
                                                   ushort* __restrict__ Qh,
                                                   ushort* __restrict__ Kh,
                                                   ushort* __restrict__ VTh) {
    __shared__ ushort Ws[64 * 200];   // W stage; reused as 64x68 transpose buf

    const int t    = threadIdx.x;
    const int wave = t >> 6, lane = t & 63;
    const int bx   = blockIdx.x;
    const int by   = blockIdx.y;
    const int m0   = bx * 64 + wave * 16;
    const int j0   = by * 64;
    const int n16  = lane & 15;
    const int kq   = lane >> 4;

    for (int rep = 0; rep < REP; ++rep) {
        __syncthreads();                 // Ws reuse across reps
        int lz = 0; asm volatile("" : "+v"(lz));   // defeat load hoisting
        const float* xL = x + lz;
        const float* wL = Wf + lz;

        for (int i = t; i < 1536; i += 256) {
            const int r = i / 24, c = i - (i / 24) * 24;
            const float* wsrc = &wL[(size_t)(j0 + r) * 192 + c * 8];
            const float4 w0 = ld4(wsrc), w1 = ld4(wsrc + 4);
            *(ushort4*)&Ws[r * 200 + c * 8] =
                make_ushort4(f2h(w0.x), f2h(w0.y), f2h(w0.z), f2h(w0.w));
            *(ushort4*)&Ws[r * 200 + c * 8 + 4] =
                make_ushort4(f2h(w1.x), f2h(w1.y), f2h(w1.z), f2h(w1.w));
        }

        if (by == 0) {                   // zero Q/K d-pads for these 64 tokens
            for (int i = t; i < 1024; i += 256) {
                const int tok = bx * 64 + (i >> 4);
                const int h_  = (i >> 1) & 7;
                ushort* dst = (i & 1) ? Kh : Qh;
                const uint4 z = {0u, 0u, 0u, 0u};
                *(uint4*)&dst[((size_t)((tok >> 11) * 8 + h_) * 2048 + (tok & 2047)) * 32 + 24] = z;
            }
        }

        const float* ap = xL + (size_t)(m0 + n16) * 192 + kq * 8;
        f16x8 af[6];
#pragma unroll
        for (int ks = 0; ks < 6; ks++) {
            const float4 a0 = ld4(ap + ks * 32);
            const float4 a1 = ld4(ap + ks * 32 + 4);
            af[ks] = cvt8(a0, a1);
        }

        f32x4 acc[4] = {f32x4{0,0,0,0}, f32x4{0,0,0,0}, f32x4{0,0,0,0}, f32x4{0,0,0,0}};

        __syncthreads();

#pragma unroll
        for (int ks = 0; ks < 6; ks++) {
#pragma unroll
            for (int nt = 0; nt < 4; nt++) {
                const f16x8 bf = *(const f16x8*)&Ws[(nt * 16 + n16) * 200 + kq * 8 + ks * 32];
                acc[nt] = __builtin_amdgcn_mfma_f32_16x16x32_f16(af[ks], bf, acc[nt], 0, 0, 0);
            }
        }

        const int band  = by / 3;        // 0=Q, 1=K, 2=V
        const int mrow0 = m0 + kq * 4;
        const int b_    = mrow0 >> 11;
        const int tok0  = mrow0 & 2047;

        if (band == 2) {                 // V -> VT[bh][d][2080]+8, direct
#pragma unroll
            for (int nt = 0; nt < 4; nt++) {
                const int col = j0 + nt * 16 + n16;
                const int lc  = col - 384;
                const int h_  = lc / 24;
                const int d_  = lc - h_ * 24;
                const float bv = bias[col];
                ushort vv[4];
#pragma unroll
                for (int r = 0; r < 4; r++) vv[r] = f2h(acc[nt][r] + bv);
                const size_t addr = ((size_t)(b_ * 8 + h_) * 32 + d_) * 2080 + 8 + tok0;
                *(ushort4*)&VTh[addr] = make_ushort4(vv[0], vv[1], vv[2], vv[3]);
            }
        } else {                         // Q/K -> LDS transpose -> coalesced
            const float sc_ = band ? 1.0f : SCALE;
            __syncthreads();             // W reads done; reuse Ws
#pragma unroll
            for (int nt = 0; nt < 4; nt++) {
                const int col = j0 + nt * 16 + n16;
                const float bv = bias[col];
#pragma unroll
                for (int r = 0; r < 4; r++) {
                    Ws[(wave * 16 + kq * 4 + r) * 68 + nt * 16 + n16] =
                        f2h((acc[nt][r] + bv) * sc_);
                }
            }
            __syncthreads();
            ushort* dst = band ? Kh : Qh;
            const int lc0 = j0 - band * 192;  // 0, 64, or 128
#pragma unroll
            for (int it = 0; it < 4; it++) {
                const int item = t + 256 * it;    // 0..1023
                const int tokl = item >> 4;
                const int cg   = item & 15;
                const ushort4 v = *(const ushort4*)&Ws[tokl * 68 + cg * 4];
                const int lc = lc0 + cg * 4;
                const int h_ = lc / 24;
                const int d0 = lc - h_ * 24;
                const int m  = bx * 64 + tokl;
                const size_t addr = ((size_t)((m >> 11) * 8 + h_) * 2048 + (m & 2047)) * 32 + d0;
                *(ushort4*)&dst[addr] = v;
            }
        }
        asm volatile("" ::: "memory");   // keep per-rep stores
    }
}

// ---------------------------------------------------------------------------
// MFMA local attention (fp16). REP'd for diagnosis.
// ---------------------------------------------------------------------------
__global__ __launch_bounds__(256, 4) void attn_mfma(const ushort* __restrict__ Qh,
                                                    const ushort* __restrict__ Kh,
                                                    const ushort* __restrict__ VTh,
                                                    ushort* __restrict__ aws) {
    const int id    = blockIdx.x;          // 0..2047
    const int head  = id & 7;              // -> XCD (id % 8 round-robin)
    const int qtile = (id >> 3) & 63;
    const int b     = id >> 9;
    const int qh0   = (qtile >> 3) * 4;
    const int qw0   = (qtile & 7) * 8;
    const int kw0a  = qw0 - 8;

    const int t = threadIdx.x;
    const int w = t >> 6, lane = t & 63;
    const int n16 = lane & 15, quad = lane >> 4;
    const int bh = b * 8 + head;

    __shared__ ushort P[32 * 328];
    __shared__ ushort Os[32 * 28];
    __shared__ float  mxbuf[64], sumbuf[64];

    for (int rep = 0; rep < REP; ++rep) {
        __syncthreads();                 // LDS reuse across reps
        int lz = 0; asm volatile("" : "+v"(lz));   // defeat load hoisting
        const ushort* Qb = Qh + lz + (size_t)bh * 65536;
        const ushort* Kb = Kh + lz + (size_t)bh * 65536;
        const ushort* VTb = VTh + lz + (size_t)bh * 66560;   // 32*2080

        const int mt = w >> 1, nth = w & 1;
        const int mrow = 16 * mt + n16;
        const int tq_a = ((qh0 + (mrow >> 3)) << 6) + qw0 + (mrow & 7);
        const f16x8 qf = *(const f16x8*)&Qb[(size_t)tq_a * 32 + quad * 8];

        float sv[10][4];
        float mx4[4] = {-3e38f, -3e38f, -3e38f, -3e38f};
#pragma unroll
        for (int half = 0; half < 2; half++) {
            f16x8 kf[5];
            int khvv[5], kwvv[5];
#pragma unroll
            for (int jj = 0; jj < 5; jj++) {       // 5 gathers in flight
                const int j = half * 5 + jj;
                const int slot = (nth * 10 + j) * 16 + n16;
                const int rr = slot >> 5, cc = slot & 31;
                khvv[jj] = qh0 - 3 + rr;
                kwvv[jj] = kw0a + cc;
                const int tok = (min(max(khvv[jj], 0), 31) << 6) + min(max(kwvv[jj], 0), 63);
                kf[jj] = *(const f16x8*)&Kb[(size_t)tok * 32 + quad * 8];
            }
#pragma unroll
            for (int jj = 0; jj < 5; jj++) {
                const int j = half * 5 + jj;
                f32x4 a = f32x4{0, 0, 0, 0};
                a = __builtin_amdgcn_mfma_f32_16x16x32_f16(qf, kf[jj], a, 0, 0, 0);
                const int khv = khvv[jj], kwv = kwvv[jj];
                const bool kok = (khv >= 0) && (khv < 32) && (kwv >= 0) && (kwv < 64);
#pragma unroll
                for (int r = 0; r < 4; r++) {
                    const int m   = 16 * mt + quad * 4 + r;
                    const int qhv = qh0 + (m >> 3);
                    const int qwv = qw0 + (m & 7);
                    const bool valid = kok && (abs(khv - qhv) <= 3) && (abs(kwv - qwv) <= 5);
                    const float s = valid ? a[r] : -3e38f;
                    sv[j][r] = s;
                    mx4[r] = fmaxf(mx4[r], s);
                }
            }
        }
#pragma unroll
        for (int d = 1; d < 16; d <<= 1)
#pragma unroll
            for (int r = 0; r < 4; r++) mx4[r] = fmaxf(mx4[r], __shfl_xor(mx4[r], d));
        if (n16 == 0) {
#pragma unroll
            for (int r = 0; r < 4; r++) mxbuf[w * 16 + quad * 4 + r] = mx4[r];
        }
        __syncthreads();
#pragma unroll
        for (int r = 0; r < 4; r++) mx4[r] = fmaxf(mx4[r], mxbuf[(w ^ 1) * 16 + quad * 4 + r]);

        float sum4[4] = {0.f, 0.f, 0.f, 0.f};
#pragma unroll
        for (int j = 0; j < 10; j++) {
            const int slot = (nth * 10 + j) * 16 + n16;
#pragma unroll
            for (int r = 0; r < 4; r++) {
                const float p = __expf(sv[j][r] - mx4[r]);
                const ushort ph = f2h(p);
                sum4[r] += h2f(ph);
                P[(16 * mt + quad * 4 + r) * 328 + slot] = ph;
            }
        }
#pragma unroll
        for (int d = 1; d < 16; d <<= 1)
#pragma unroll
            for (int r = 0; r < 4; r++) sum4[r] += __shfl_xor(sum4[r], d);
        if (n16 == 0) {
#pragma unroll
            for (int r = 0; r < 4; r++) sumbuf[w * 16 + quad * 4 + r] = sum4[r];
        }
        __syncthreads();

        // ---- PV: VT gathers hoisted in batches of 5 ----
        const int mtP = w >> 1, ntP = w & 1;
        const int dcol = 16 * ntP + n16;
        f32x4 acc = f32x4{0, 0, 0, 0};
#pragma unroll
        for (int half = 0; half < 2; half++) {
            f16x8 vf[5], pa[5];
#pragma unroll
            for (int kk = 0; kk < 5; kk++) {
                const int ks = half * 5 + kk;
                const int kh_cl = min(max(qh0 - 3 + ks, 0), 31);
                vf[kk] = *(const f16x8*)&VTb[(size_t)dcol * 2080 + 8 + (kh_cl << 6) + kw0a + quad * 8];
                pa[kk] = *(const f16x8*)&P[(16 * mtP + n16) * 328 + ks * 32 + quad * 8];
            }
#pragma unroll
            for (int kk = 0; kk < 5; kk++) {
                acc = __builtin_amdgcn_mfma_f32_16x16x32_f16(pa[kk], vf[kk], acc, 0, 0, 0);
            }
        }
        if (dcol < 24) {
#pragma unroll
            for (int r = 0; r < 4; r++) {
                const int m = 16 * mtP + quad * 4 + r;
                const float tot = sumbuf[(2 * mtP) * 16 + (m & 15)] +
                                  sumbuf[(2 * mtP + 1) * 16 + (m & 15)];
                Os[m * 28 + dcol] = f2h(acc[r] / tot);
            }
        }
        __syncthreads();

        // ---- coalesced output: 32 tokens x 24 dims ----
        if (t < 192) {
            const int tok = t / 6, g = t - (t / 6) * 6;
            const ushort4 v = *(const ushort4*)&Os[tok * 28 + g * 4];
            const int tq = ((qh0 + (tok >> 3)) << 6) + qw0 + (tok & 7);
            *(ushort4*)&aws[((size_t)(b * 2048 + tq)) * 192 + head * 24 + g * 4] = v;
        }
        asm volatile("" ::: "memory");   // keep per-rep stores
    }
}

// ---------------------------------------------------------------------------
// Proj GEMM (fp16 MFMA), inline W cast. REP'd for diagnosis.
// ---------------------------------------------------------------------------
__global__ __launch_bounds__(128, 4) void gemm_proj(const ushort* __restrict__ Ah,
                                                    const float* __restrict__ Wf,
                                                    const float* __restrict__ bias,
                                                    float* __restrict__ C) {
    __shared__ ushort Ws[64 * 200];

    const int t    = threadIdx.x;
    const int wave = t >> 6, lane = t & 63;
    const int m0   = blockIdx.x * 32 + wave * 16;
    const int j0   = blockIdx.y * 64;
    const int n16  = lane & 15;
    const int kq   = lane >> 4;

    for (int rep = 0; rep < REP; ++rep) {
        __syncthreads();                 // Ws reuse across reps
        int lz = 0; asm volatile("" : "+v"(lz));   // defeat load hoisting
        const ushort* aL = Ah + lz;
        const float*  wL = Wf + lz;

        for (int i = t; i < 1536; i += 128) {
            const int r = i / 24, c = i - (i / 24) * 24;
            const float* wsrc = &wL[(size_t)(j0 + r) * 192 + c * 8];
            const float4 w0 = ld4(wsrc), w1 = ld4(wsrc + 4);
            *(ushort4*)&Ws[r * 200 + c * 8] =
                make_ushort4(f2h(w0.x), f2h(w0.y), f2h(w0.z), f2h(w0.w));
            *(ushort4*)&Ws[r * 200 + c * 8 + 4] =
                make_ushort4(f2h(w1.x), f2h(w1.y), f2h(w1.z), f2h(w1.w));
        }

        const ushort* ap = aL + (size_t)(m0 + n16) * 192 + kq * 8;

        f16x8 af[6];
#pragma unroll
        for (int ks = 0; ks < 6; ks++) af[ks] = *(const f16x8*)(ap + ks * 32);

        f32x4 acc[4] = {f32x4{0,0,0,0}, f32x4{0,0,0,0}, f32x4{0,0,0,0}, f32x4{0,0,0,0}};

        __syncthreads();

#pragma unroll
        for (int ks = 0; ks < 6; ks++) {
#pragma unroll
            for (int nt = 0; nt < 4; nt++) {
                const f16x8 bf = *(const f16x8*)&Ws[(nt * 16 + n16) * 200 + kq * 8 + ks * 32];
                acc[nt] = __builtin_amdgcn_mfma_f32_16x16x32_f16(af[ks], bf, acc[nt], 0, 0, 0);
            }
        }

#pragma unroll
        for (int nt = 0; nt < 4; nt++) {
            const int col = j0 + nt * 16 + n16;
            const float bv = bias[col];
#pragma unroll
            for (int r = 0; r < 4; r++) {
                const int m = m0 + kq * 4 + r;
                C[(size_t)m * 192 + col] = acc[nt][r] + bv;
            }
        }
        asm volatile("" ::: "memory");   // keep per-rep stores
    }
}

// ---------------------------------------------------------------------------
// Launch: gemm_qkv -> attn_mfma -> gemm_proj (each REP'd for diagnosis)
// ---------------------------------------------------------------------------
extern "C" void kernel_launch(void* const* d_in, const int* in_sizes, int n_in,
                              void* d_out, int out_size, void* d_ws, size_t ws_size,
                              hipStream_t stream) {
    const float* x      = (const float*)d_in[0];
    const float* qkv_w  = (const float*)d_in[1];
    const float* qkv_b  = (const float*)d_in[2];
    const float* proj_w = (const float*)d_in[3];
    const float* proj_b = (const float*)d_in[4];
    // d_in[5] mask: fixed 7x11 window, recomputed analytically; unused.

    char* wsb = (char*)d_ws;
    ushort* Qh   = (ushort*)(wsb + 0);          // [32,2048,32] fp16
    ushort* Kh   = (ushort*)(wsb + 4194304);    // [32,2048,32]
    ushort* VTh  = (ushort*)(wsb + 8388608);    // [32,32,2080]
    ushort* awsh = (ushort*)(wsb + 12648448);   // [8192,192]
    float*  out  = (float*)d_out;

    hipLaunchKernelGGL(gemm_qkv, dim3(128, 9), dim3(256), 0, stream,
                       x, qkv_w, qkv_b, Qh, Kh, VTh);
    hipLaunchKernelGGL(attn_mfma, dim3(2048), dim3(256), 0, stream,
                       Qh, Kh, VTh, awsh);
    hipLaunchKernelGGL(gemm_proj, dim3(256, 3), dim3(128), 0, stream,
                       awsh, proj_w, proj_b, out);
}

// Round 5
// 113.087 us; speedup vs baseline: 3.0892x; 2.1794x over previous
//
#include <hip/hip_runtime.h>
#include <math.h>

// Problem constants
#define H_GRID 32
#define W_GRID 64
#define NTOK   2048
#define NHEADS 8
#define HD     24
#define DIMC   192
#define BATCH  4

static constexpr float SCALE = 0.20412414523193154f; // 1/sqrt(24)

typedef unsigned short ushort;
typedef unsigned int   uint;
typedef __attribute__((ext_vector_type(8))) _Float16 f16x8;
typedef __attribute__((ext_vector_type(4))) float    f32x4;

static __device__ __forceinline__ float4 ld4(const float* p) { return *(const float4*)p; }

static __device__ __forceinline__ ushort f2h(float f) {
    _Float16 h = (_Float16)f;
    union { _Float16 h; ushort u; } c; c.h = h; return c.u;
}
static __device__ __forceinline__ float h2f(ushort u) {
    union { ushort u; _Float16 h; } c; c.u = u; return (float)c.h;
}
static __device__ __forceinline__ f16x8 cvt8(float4 a, float4 b) {
    f16x8 r;
    r[0] = (_Float16)a.x; r[1] = (_Float16)a.y; r[2] = (_Float16)a.z; r[3] = (_Float16)a.w;
    r[4] = (_Float16)b.x; r[5] = (_Float16)b.y; r[6] = (_Float16)b.z; r[7] = (_Float16)b.w;
    return r;
}

// ---------------------------------------------------------------------------
// QKV GEMM (fp16 MFMA), inline fp32->fp16 cast, 128 rows/block (two MFMA
// passes A/B sharing one staged W-tile -> W-staging traffic halved vs R2).
//   Q/K: [bh][tok][32] fp16 (d-pads zeroed by by==0 tiles), q scaled
//   V:   VT [bh][d(32 rows, 24 used)][2080] fp16, token offset +8
// ---------------------------------------------------------------------------
__global__ __launch_bounds__(256, 4) void gemm_qkv(const float* __restrict__ x,
                                                   const float* __restrict__ Wf,
                                                   const float* __restrict__ bias,
                                                   ushort* __restrict__ Qh,
                                                   ushort* __restrict__ Kh,
                                                   ushort* __restrict__ VTh) {
    __shared__ ushort Ws[64 * 200];   // W stage; reused as 128x68 transpose buf

    const int t    = threadIdx.x;
    const int wave = t >> 6, lane = t & 63;
    const int bx   = blockIdx.x;
    const int by   = blockIdx.y;
    const int j0   = by * 64;
    const int n16  = lane & 15;
    const int kq   = lane >> 4;
    const int mA   = bx * 128 + wave * 16;
    const int mB   = mA + 64;

    // Stage W tile with inline cast: 64 rows x 192 cols fp32 -> fp16
    for (int i = t; i < 1536; i += 256) {
        const int r = i / 24, c = i - (i / 24) * 24;
        const float* wsrc = &Wf[(size_t)(j0 + r) * 192 + c * 8];
        const float4 w0 = ld4(wsrc), w1 = ld4(wsrc + 4);
        *(ushort4*)&Ws[r * 200 + c * 8] =
            make_ushort4(f2h(w0.x), f2h(w0.y), f2h(w0.z), f2h(w0.w));
        *(ushort4*)&Ws[r * 200 + c * 8 + 4] =
            make_ushort4(f2h(w1.x), f2h(w1.y), f2h(w1.z), f2h(w1.w));
    }

    if (by == 0) {                       // zero Q/K d-pads for these 128 tokens
        for (int i = t; i < 2048; i += 256) {
            const int tok = bx * 128 + (i >> 4);
            const int h_  = (i >> 1) & 7;
            ushort* dst = (i & 1) ? Kh : Qh;
            const uint4 z = {0u, 0u, 0u, 0u};
            *(uint4*)&dst[((size_t)((tok >> 11) * 8 + h_) * 2048 + (tok & 2047)) * 32 + 24] = z;
        }
    }

    // A fragments for both row-halves (fp32 load + inline cast)
    const float* apA = x + (size_t)(mA + n16) * 192 + kq * 8;
    const float* apB = apA + 64 * 192;
    f16x8 afA[6], afB[6];
#pragma unroll
    for (int ks = 0; ks < 6; ks++) {
        afA[ks] = cvt8(ld4(apA + ks * 32), ld4(apA + ks * 32 + 4));
        afB[ks] = cvt8(ld4(apB + ks * 32), ld4(apB + ks * 32 + 4));
    }

    f32x4 accA[4] = {f32x4{0,0,0,0}, f32x4{0,0,0,0}, f32x4{0,0,0,0}, f32x4{0,0,0,0}};
    f32x4 accB[4] = {f32x4{0,0,0,0}, f32x4{0,0,0,0}, f32x4{0,0,0,0}, f32x4{0,0,0,0}};

    __syncthreads();

#pragma unroll
    for (int ks = 0; ks < 6; ks++) {
#pragma unroll
        for (int nt = 0; nt < 4; nt++) {
            const f16x8 bf = *(const f16x8*)&Ws[(nt * 16 + n16) * 200 + kq * 8 + ks * 32];
            accA[nt] = __builtin_amdgcn_mfma_f32_16x16x32_f16(afA[ks], bf, accA[nt], 0, 0, 0);
            accB[nt] = __builtin_amdgcn_mfma_f32_16x16x32_f16(afB[ks], bf, accB[nt], 0, 0, 0);
        }
    }

    const int band = by / 3;             // 0=Q, 1=K, 2=V

    if (band == 2) {                     // V -> VT[bh][d][2080]+8, direct
        const int rowA = mA + kq * 4, rowB = mB + kq * 4;
#pragma unroll
        for (int nt = 0; nt < 4; nt++) {
            const int col = j0 + nt * 16 + n16;
            const int lc  = col - 384;
            const int h_  = lc / 24;
            const int d_  = lc - h_ * 24;
            const float bv = bias[col];
            ushort vvA[4], vvB[4];
#pragma unroll
            for (int r = 0; r < 4; r++) {
                vvA[r] = f2h(accA[nt][r] + bv);
                vvB[r] = f2h(accB[nt][r] + bv);
            }
            const size_t baseA = ((size_t)((rowA >> 11) * 8 + h_) * 32 + d_) * 2080 + 8 + (rowA & 2047);
            const size_t baseB = ((size_t)((rowB >> 11) * 8 + h_) * 32 + d_) * 2080 + 8 + (rowB & 2047);
            *(ushort4*)&VTh[baseA] = make_ushort4(vvA[0], vvA[1], vvA[2], vvA[3]);
            *(ushort4*)&VTh[baseB] = make_ushort4(vvB[0], vvB[1], vvB[2], vvB[3]);
        }
    } else {                             // Q/K -> LDS transpose -> coalesced
        const float sc_ = band ? 1.0f : SCALE;
        __syncthreads();                 // W reads done; reuse Ws as [128][68]
#pragma unroll
        for (int nt = 0; nt < 4; nt++) {
            const int col = j0 + nt * 16 + n16;
            const float bv = bias[col];
#pragma unroll
            for (int r = 0; r < 4; r++) {
                Ws[(wave * 16 + kq * 4 + r) * 68 + nt * 16 + n16] =
                    f2h((accA[nt][r] + bv) * sc_);
                Ws[(64 + wave * 16 + kq * 4 + r) * 68 + nt * 16 + n16] =
                    f2h((accB[nt][r] + bv) * sc_);
            }
        }
        __syncthreads();
        ushort* dst = band ? Kh : Qh;
        const int lc0 = j0 - band * 192; // 0, 64, or 128
#pragma unroll
        for (int it = 0; it < 8; it++) {
            const int item = t + 256 * it;    // 0..2047
            const int tokl = item >> 4;       // 0..127
            const int cg   = item & 15;
            const ushort4 v = *(const ushort4*)&Ws[tokl * 68 + cg * 4];
            const int lc = lc0 + cg * 4;
            const int h_ = lc / 24;
            const int d0 = lc - h_ * 24;
            const int m  = bx * 128 + tokl;
            const size_t addr = ((size_t)((m >> 11) * 8 + h_) * 2048 + (m & 2047)) * 32 + d0;
            *(ushort4*)&dst[addr] = v;
        }
    }
}

// ---------------------------------------------------------------------------
// MFMA local attention (fp16), XCD-pinned (blockIdx.x & 7 = head).
// R4 counters: VALUBusy 46%, MfmaUtil 7% -> VALU/latency-bound. Changes vs
// verified R2 body: (1) interior window mask precomputed into a per-thread
// 40-bit constant (block-independent: dh=rr-3-(m>>3), dw=cc-8-(m&7));
// (2) O stored directly to global from PV acc (drops Os LDS + 1 barrier;
// LDS 23.5->21.5 KB -> 7 blocks/CU); (3) rcp+mul instead of 4 divides.
// ---------------------------------------------------------------------------
__global__ __launch_bounds__(256, 4) void attn_mfma(const ushort* __restrict__ Qh,
                                                    const ushort* __restrict__ Kh,
                                                    const ushort* __restrict__ VTh,
                                                    ushort* __restrict__ aws) {
    const int id    = blockIdx.x;          // 0..2047
    const int head  = id & 7;              // -> XCD (id % 8 round-robin)
    const int qtile = (id >> 3) & 63;
    const int b     = id >> 9;
    const int qh0   = (qtile >> 3) * 4;
    const int qw0   = (qtile & 7) * 8;
    const int kw0a  = qw0 - 8;

    const int t = threadIdx.x;
    const int w = t >> 6, lane = t & 63;
    const int n16 = lane & 15, quad = lane >> 4;
    const int bh = b * 8 + head;

    __shared__ ushort P[32 * 328];
    __shared__ float  mxbuf[64], sumbuf[64];

    const ushort* Qb = Qh + (size_t)bh * 65536;
    const ushort* Kb = Kh + (size_t)bh * 65536;

    const int mt = w >> 1, nth = w & 1;

    // Per-thread interior-validity mask (block-independent): bit j*4+r set iff
    // |khv-qhv|<=3 && |kwv-qwv|<=5 for that (j,r) at this lane position.
    unsigned long long imask = 0ull;
#pragma unroll
    for (int j = 0; j < 10; j++) {
        const int slot = (nth * 10 + j) * 16 + n16;
        const int rr = slot >> 5, cc = slot & 31;
#pragma unroll
        for (int r = 0; r < 4; r++) {
            const int m  = 16 * mt + quad * 4 + r;
            const int dh = rr - 3 - (m >> 3);
            const int dw = cc - 8 - (m & 7);
            if (abs(dh) <= 3 && abs(dw) <= 5) imask |= 1ull << (j * 4 + r);
        }
    }

    const int mrow = 16 * mt + n16;
    const int tq_a = ((qh0 + (mrow >> 3)) << 6) + qw0 + (mrow & 7);
    const f16x8 qf = *(const f16x8*)&Qb[(size_t)tq_a * 32 + quad * 8];

    float sv[10][4];
    float mx4[4] = {-3e38f, -3e38f, -3e38f, -3e38f};
#pragma unroll
    for (int half = 0; half < 2; half++) {
        f16x8 kf[5];
        int khvv[5], kwvv[5];
#pragma unroll
        for (int jj = 0; jj < 5; jj++) {       // 5 gathers in flight
            const int j = half * 5 + jj;
            const int slot = (nth * 10 + j) * 16 + n16;
            const int rr = slot >> 5, cc = slot & 31;
            khvv[jj] = qh0 - 3 + rr;
            kwvv[jj] = kw0a + cc;
            const int tok = (min(max(khvv[jj], 0), 31) << 6) + min(max(kwvv[jj], 0), 63);
            kf[jj] = *(const f16x8*)&Kb[(size_t)tok * 32 + quad * 8];
        }
#pragma unroll
        for (int jj = 0; jj < 5; jj++) {
            const int j = half * 5 + jj;
            f32x4 a = f32x4{0, 0, 0, 0};
            a = __builtin_amdgcn_mfma_f32_16x16x32_f16(qf, kf[jj], a, 0, 0, 0);
            const int khv = khvv[jj], kwv = kwvv[jj];
            const bool kok = (khv >= 0) && (khv < 32) && (kwv >= 0) && (kwv < 64);
#pragma unroll
            for (int r = 0; r < 4; r++) {
                const bool valid = kok && ((imask >> (j * 4 + r)) & 1);
                const float s = valid ? a[r] : -3e38f;
                sv[j][r] = s;
                mx4[r] = fmaxf(mx4[r], s);
            }
        }
    }
#pragma unroll
    for (int d = 1; d < 16; d <<= 1)
#pragma unroll
        for (int r = 0; r < 4; r++) mx4[r] = fmaxf(mx4[r], __shfl_xor(mx4[r], d));
    if (n16 == 0) {
#pragma unroll
        for (int r = 0; r < 4; r++) mxbuf[w * 16 + quad * 4 + r] = mx4[r];
    }
    __syncthreads();
#pragma unroll
    for (int r = 0; r < 4; r++) mx4[r] = fmaxf(mx4[r], mxbuf[(w ^ 1) * 16 + quad * 4 + r]);

    float sum4[4] = {0.f, 0.f, 0.f, 0.f};
#pragma unroll
    for (int j = 0; j < 10; j++) {
        const int slot = (nth * 10 + j) * 16 + n16;
#pragma unroll
        for (int r = 0; r < 4; r++) {
            const float p = __expf(sv[j][r] - mx4[r]);
            const ushort ph = f2h(p);
            sum4[r] += h2f(ph);
            P[(16 * mt + quad * 4 + r) * 328 + slot] = ph;
        }
    }
#pragma unroll
    for (int d = 1; d < 16; d <<= 1)
#pragma unroll
        for (int r = 0; r < 4; r++) sum4[r] += __shfl_xor(sum4[r], d);
    if (n16 == 0) {
#pragma unroll
        for (int r = 0; r < 4; r++) sumbuf[w * 16 + quad * 4 + r] = sum4[r];
    }
    __syncthreads();

    // ---- PV: VT gathers hoisted in batches of 5 ----
    const int mtP = w >> 1, ntP = w & 1;
    const int dcol = 16 * ntP + n16;
    const ushort* VTb = VTh + (size_t)bh * 66560;    // 32*2080
    f32x4 acc = f32x4{0, 0, 0, 0};
#pragma unroll
    for (int half = 0; half < 2; half++) {
        f16x8 vf[5], pa[5];
#pragma unroll
        for (int kk = 0; kk < 5; kk++) {
            const int ks = half * 5 + kk;
            const int kh_cl = min(max(qh0 - 3 + ks, 0), 31);
            vf[kk] = *(const f16x8*)&VTb[(size_t)dcol * 2080 + 8 + (kh_cl << 6) + kw0a + quad * 8];
            pa[kk] = *(const f16x8*)&P[(16 * mtP + n16) * 328 + ks * 32 + quad * 8];
        }
#pragma unroll
        for (int kk = 0; kk < 5; kk++) {
            acc = __builtin_amdgcn_mfma_f32_16x16x32_f16(pa[kk], vf[kk], acc, 0, 0, 0);
        }
    }

    // ---- direct O store (waves cover disjoint (row,dcol) sets) ----
    if (dcol < 24) {
#pragma unroll
        for (int r = 0; r < 4; r++) {
            const int m = 16 * mtP + quad * 4 + r;
            const float tot = sumbuf[(2 * mtP) * 16 + quad * 4 + r] +
                              sumbuf[(2 * mtP + 1) * 16 + quad * 4 + r];
            const float rt = __builtin_amdgcn_rcpf(tot);
            const int tq = ((qh0 + (m >> 3)) << 6) + qw0 + (m & 7);
            aws[((size_t)(b * 2048 + tq)) * 192 + head * 24 + dcol] = f2h(acc[r] * rt);
        }
    }
}

// ---------------------------------------------------------------------------
// Proj GEMM (fp16 MFMA), inline W cast, 128 rows/block, 256 threads (two
// MFMA passes sharing one staged W-tile -> staging traffic /4 vs R2).
// out[8192x192] = aws @ Wp^T + bias (fp32 out).
// ---------------------------------------------------------------------------
__global__ __launch_bounds__(256, 4) void gemm_proj(const ushort* __restrict__ Ah,
                                                    const float* __restrict__ Wf,
                                                    const float* __restrict__ bias,
                                                    float* __restrict__ C) {
    __shared__ ushort Ws[64 * 200];

    const int t    = threadIdx.x;
    const int wave = t >> 6, lane = t & 63;
    const int j0   = blockIdx.y * 64;
    const int n16  = lane & 15;
    const int kq   = lane >> 4;
    const int mA   = blockIdx.x * 128 + wave * 16;
    const int mB   = mA + 64;

    for (int i = t; i < 1536; i += 256) {
        const int r = i / 24, c = i - (i / 24) * 24;
        const float* wsrc = &Wf[(size_t)(j0 + r) * 192 + c * 8];
        const float4 w0 = ld4(wsrc), w1 = ld4(wsrc + 4);
        *(ushort4*)&Ws[r * 200 + c * 8] =
            make_ushort4(f2h(w0.x), f2h(w0.y), f2h(w0.z), f2h(w0.w));
        *(ushort4*)&Ws[r * 200 + c * 8 + 4] =
            make_ushort4(f2h(w1.x), f2h(w1.y), f2h(w1.z), f2h(w1.w));
    }

    const ushort* apA = Ah + (size_t)(mA + n16) * 192 + kq * 8;
    const ushort* apB = apA + 64 * 192;

    f16x8 afA[6], afB[6];
#pragma unroll
    for (int ks = 0; ks < 6; ks++) {
        afA[ks] = *(const f16x8*)(apA + ks * 32);
        afB[ks] = *(const f16x8*)(apB + ks * 32);
    }

    f32x4 accA[4] = {f32x4{0,0,0,0}, f32x4{0,0,0,0}, f32x4{0,0,0,0}, f32x4{0,0,0,0}};
    f32x4 accB[4] = {f32x4{0,0,0,0}, f32x4{0,0,0,0}, f32x4{0,0,0,0}, f32x4{0,0,0,0}};

    __syncthreads();

#pragma unroll
    for (int ks = 0; ks < 6; ks++) {
#pragma unroll
        for (int nt = 0; nt < 4; nt++) {
            const f16x8 bf = *(const f16x8*)&Ws[(nt * 16 + n16) * 200 + kq * 8 + ks * 32];
            accA[nt] = __builtin_amdgcn_mfma_f32_16x16x32_f16(afA[ks], bf, accA[nt], 0, 0, 0);
            accB[nt] = __builtin_amdgcn_mfma_f32_16x16x32_f16(afB[ks], bf, accB[nt], 0, 0, 0);
        }
    }

#pragma unroll
    for (int nt = 0; nt < 4; nt++) {
        const int col = j0 + nt * 16 + n16;
        const float bv = bias[col];
#pragma unroll
        for (int r = 0; r < 4; r++) {
            C[(size_t)(mA + kq * 4 + r) * 192 + col] = accA[nt][r] + bv;
            C[(size_t)(mB + kq * 4 + r) * 192 + col] = accB[nt][r] + bv;
        }
    }
}

// ---------------------------------------------------------------------------
// Launch: gemm_qkv (64,9) -> attn_mfma (2048) -> gemm_proj (64,3)
// ---------------------------------------------------------------------------
extern "C" void kernel_launch(void* const* d_in, const int* in_sizes, int n_in,
                              void* d_out, int out_size, void* d_ws, size_t ws_size,
                              hipStream_t stream) {
    const float* x      = (const float*)d_in[0];
    const float* qkv_w  = (const float*)d_in[1];
    const float* qkv_b  = (const float*)d_in[2];
    const float* proj_w = (const float*)d_in[3];
    const float* proj_b = (const float*)d_in[4];
    // d_in[5] mask: fixed 7x11 window, recomputed analytically; unused.

    char* wsb = (char*)d_ws;
    ushort* Qh   = (ushort*)(wsb + 0);          // [32,2048,32] fp16
    ushort* Kh   = (ushort*)(wsb + 4194304);    // [32,2048,32]
    ushort* VTh  = (ushort*)(wsb + 8388608);    // [32,32,2080]
    ushort* awsh = (ushort*)(wsb + 12648448);   // [8192,192]
    float*  out  = (float*)d_out;

    hipLaunchKernelGGL(gemm_qkv, dim3(64, 9), dim3(256), 0, stream,
                       x, qkv_w, qkv_b, Qh, Kh, VTh);
    hipLaunchKernelGGL(attn_mfma, dim3(2048), dim3(256), 0, stream,
                       Qh, Kh, VTh, awsh);
    hipLaunchKernelGGL(gemm_proj, dim3(64, 3), dim3(256), 0, stream,
                       awsh, proj_w, proj_b, out);
}

// Round 6
// 110.493 us; speedup vs baseline: 3.1617x; 1.0235x over previous
//
#include <hip/hip_runtime.h>
#include <math.h>

// Problem constants
#define H_GRID 32
#define W_GRID 64
#define NTOK   2048
#define NHEADS 8
#define HD     24
#define DIMC   192
#define BATCH  4

static constexpr float SCALE = 0.20412414523193154f; // 1/sqrt(24)

typedef unsigned short ushort;
typedef unsigned int   uint;
typedef __attribute__((ext_vector_type(8))) _Float16 f16x8;
typedef __attribute__((ext_vector_type(4))) float    f32x4;

static __device__ __forceinline__ float4 ld4(const float* p) { return *(const float4*)p; }

static __device__ __forceinline__ ushort f2h(float f) {
    _Float16 h = (_Float16)f;
    union { _Float16 h; ushort u; } c; c.h = h; return c.u;
}
static __device__ __forceinline__ float h2f(ushort u) {
    union { ushort u; _Float16 h; } c; c.u = u; return (float)c.h;
}
static __device__ __forceinline__ f16x8 cvt8(float4 a, float4 b) {
    f16x8 r;
    r[0] = (_Float16)a.x; r[1] = (_Float16)a.y; r[2] = (_Float16)a.z; r[3] = (_Float16)a.w;
    r[4] = (_Float16)b.x; r[5] = (_Float16)b.y; r[6] = (_Float16)b.z; r[7] = (_Float16)b.w;
    return r;
}

// ---------------------------------------------------------------------------
// QKV GEMM (fp16 MFMA), inline fp32->fp16 cast (R2-verified structure:
// 64 rows/block, grid 128x9). by==0 tiles zero Q/K d-pads (24..31).
//   Q/K: [bh][tok][32] fp16, q scaled
//   V:   VT [bh][d(32 rows, 24 used)][2080] fp16, token offset +8
// ---------------------------------------------------------------------------
__global__ __launch_bounds__(256, 4) void gemm_qkv(const float* __restrict__ x,
                                                   const float* __restrict__ Wf,
                                                   const float* __restrict__ bias,
                                                   ushort* __restrict__ Qh,
                                                   ushort* __restrict__ Kh,
                                                   ushort* __restrict__ VTh) {
    __shared__ ushort Ws[64 * 200];   // W stage; reused as 64x68 transpose buf

    const int t    = threadIdx.x;
    const int wave = t >> 6, lane = t & 63;
    const int bx   = blockIdx.x;
    const int by   = blockIdx.y;
    const int m0   = bx * 64 + wave * 16;
    const int j0   = by * 64;
    const int n16  = lane & 15;
    const int kq   = lane >> 4;

    // Stage W tile with inline cast: 64 rows x 192 cols fp32 -> fp16
    for (int i = t; i < 1536; i += 256) {
        const int r = i / 24, c = i - (i / 24) * 24;
        const float* wsrc = &Wf[(size_t)(j0 + r) * 192 + c * 8];
        const float4 w0 = ld4(wsrc), w1 = ld4(wsrc + 4);
        *(ushort4*)&Ws[r * 200 + c * 8] =
            make_ushort4(f2h(w0.x), f2h(w0.y), f2h(w0.z), f2h(w0.w));
        *(ushort4*)&Ws[r * 200 + c * 8 + 4] =
            make_ushort4(f2h(w1.x), f2h(w1.y), f2h(w1.z), f2h(w1.w));
    }

    if (by == 0) {                       // zero Q/K d-pads for these 64 tokens
        for (int i = t; i < 1024; i += 256) {
            const int tok = bx * 64 + (i >> 4);
            const int h_  = (i >> 1) & 7;
            ushort* dst = (i & 1) ? Kh : Qh;
            const uint4 z = {0u, 0u, 0u, 0u};
            *(uint4*)&dst[((size_t)((tok >> 11) * 8 + h_) * 2048 + (tok & 2047)) * 32 + 24] = z;
        }
    }

    // A fragments: fp32 load + inline cast (6 in flight)
    const float* ap = x + (size_t)(m0 + n16) * 192 + kq * 8;
    f16x8 af[6];
#pragma unroll
    for (int ks = 0; ks < 6; ks++) {
        const float4 a0 = ld4(ap + ks * 32);
        const float4 a1 = ld4(ap + ks * 32 + 4);
        af[ks] = cvt8(a0, a1);
    }

    f32x4 acc[4] = {f32x4{0,0,0,0}, f32x4{0,0,0,0}, f32x4{0,0,0,0}, f32x4{0,0,0,0}};

    __syncthreads();

#pragma unroll
    for (int ks = 0; ks < 6; ks++) {
#pragma unroll
        for (int nt = 0; nt < 4; nt++) {
            const f16x8 bf = *(const f16x8*)&Ws[(nt * 16 + n16) * 200 + kq * 8 + ks * 32];
            acc[nt] = __builtin_amdgcn_mfma_f32_16x16x32_f16(af[ks], bf, acc[nt], 0, 0, 0);
        }
    }

    const int band  = by / 3;         // 0=Q, 1=K, 2=V
    const int mrow0 = m0 + kq * 4;
    const int b_    = mrow0 >> 11;
    const int tok0  = mrow0 & 2047;

    if (band == 2) {                          // V -> VT[bh][d][2080]+8, direct
#pragma unroll
        for (int nt = 0; nt < 4; nt++) {
            const int col = j0 + nt * 16 + n16;
            const int lc  = col - 384;
            const int h_  = lc / 24;
            const int d_  = lc - h_ * 24;
            const float bv = bias[col];
            ushort vv[4];
#pragma unroll
            for (int r = 0; r < 4; r++) vv[r] = f2h(acc[nt][r] + bv);
            const size_t addr = ((size_t)(b_ * 8 + h_) * 32 + d_) * 2080 + 8 + tok0;
            *(ushort4*)&VTh[addr] = make_ushort4(vv[0], vv[1], vv[2], vv[3]);
        }
    } else {                                  // Q/K -> LDS transpose -> coalesced
        const float sc_ = band ? 1.0f : SCALE;
        __syncthreads();                      // W reads done; reuse Ws
#pragma unroll
        for (int nt = 0; nt < 4; nt++) {
            const int col = j0 + nt * 16 + n16;
            const float bv = bias[col];
#pragma unroll
            for (int r = 0; r < 4; r++) {
                Ws[(wave * 16 + kq * 4 + r) * 68 + nt * 16 + n16] =
                    f2h((acc[nt][r] + bv) * sc_);
            }
        }
        __syncthreads();
        ushort* dst = band ? Kh : Qh;
        const int lc0 = j0 - band * 192;      // 0, 64, or 128
#pragma unroll
        for (int it = 0; it < 4; it++) {
            const int item = t + 256 * it;    // 0..1023
            const int tokl = item >> 4;
            const int cg   = item & 15;
            const ushort4 v = *(const ushort4*)&Ws[tokl * 68 + cg * 4];
            const int lc = lc0 + cg * 4;
            const int h_ = lc / 24;
            const int d0 = lc - h_ * 24;
            const int m  = bx * 64 + tokl;
            const size_t addr = ((size_t)((m >> 11) * 8 + h_) * 2048 + (m & 2047)) * 32 + d0;
            *(ushort4*)&dst[addr] = v;
        }
    }
}

// ---------------------------------------------------------------------------
// MFMA local attention (fp16), XCD-pinned (blockIdx.x & 7 = head).
// R2-verified memory structure (Os LDS staging + coalesced ushort4 output)
// with two VALU-only changes, R5-verified numerically safe:
//  (1) interior window mask precomputed into a per-thread 40-bit constant
//      (block-independent: dh=rr-3-(m>>3), dw=cc-8-(m&7));
//  (2) rcp+mul instead of 4 divides in the epilogue.
// ---------------------------------------------------------------------------
__global__ __launch_bounds__(256, 4) void attn_mfma(const ushort* __restrict__ Qh,
                                                    const ushort* __restrict__ Kh,
                                                    const ushort* __restrict__ VTh,
                                                    ushort* __restrict__ aws) {
    const int id    = blockIdx.x;          // 0..2047
    const int head  = id & 7;              // -> XCD (id % 8 round-robin)
    const int qtile = (id >> 3) & 63;
    const int b     = id >> 9;
    const int qh0   = (qtile >> 3) * 4;
    const int qw0   = (qtile & 7) * 8;
    const int kw0a  = qw0 - 8;

    const int t = threadIdx.x;
    const int w = t >> 6, lane = t & 63;
    const int n16 = lane & 15, quad = lane >> 4;
    const int bh = b * 8 + head;

    __shared__ ushort P[32 * 328];
    __shared__ ushort Os[32 * 28];
    __shared__ float  mxbuf[64], sumbuf[64];

    const ushort* Qb = Qh + (size_t)bh * 65536;
    const ushort* Kb = Kh + (size_t)bh * 65536;

    const int mt = w >> 1, nth = w & 1;

    // Per-thread interior-validity mask (block-independent): bit j*4+r set iff
    // |khv-qhv|<=3 && |kwv-qwv|<=5 for that (j,r) at this lane position.
    unsigned long long imask = 0ull;
#pragma unroll
    for (int j = 0; j < 10; j++) {
        const int slot = (nth * 10 + j) * 16 + n16;
        const int rr = slot >> 5, cc = slot & 31;
#pragma unroll
        for (int r = 0; r < 4; r++) {
            const int m  = 16 * mt + quad * 4 + r;
            const int dh = rr - 3 - (m >> 3);
            const int dw = cc - 8 - (m & 7);
            if (abs(dh) <= 3 && abs(dw) <= 5) imask |= 1ull << (j * 4 + r);
        }
    }

    const int mrow = 16 * mt + n16;
    const int tq_a = ((qh0 + (mrow >> 3)) << 6) + qw0 + (mrow & 7);
    const f16x8 qf = *(const f16x8*)&Qb[(size_t)tq_a * 32 + quad * 8];

    float sv[10][4];
    float mx4[4] = {-3e38f, -3e38f, -3e38f, -3e38f};
#pragma unroll
    for (int half = 0; half < 2; half++) {
        f16x8 kf[5];
        int khvv[5], kwvv[5];
#pragma unroll
        for (int jj = 0; jj < 5; jj++) {       // 5 gathers in flight
            const int j = half * 5 + jj;
            const int slot = (nth * 10 + j) * 16 + n16;
            const int rr = slot >> 5, cc = slot & 31;
            khvv[jj] = qh0 - 3 + rr;
            kwvv[jj] = kw0a + cc;
            const int tok = (min(max(khvv[jj], 0), 31) << 6) + min(max(kwvv[jj], 0), 63);
            kf[jj] = *(const f16x8*)&Kb[(size_t)tok * 32 + quad * 8];
        }
#pragma unroll
        for (int jj = 0; jj < 5; jj++) {
            const int j = half * 5 + jj;
            f32x4 a = f32x4{0, 0, 0, 0};
            a = __builtin_amdgcn_mfma_f32_16x16x32_f16(qf, kf[jj], a, 0, 0, 0);
            const int khv = khvv[jj], kwv = kwvv[jj];
            const bool kok = (khv >= 0) && (khv < 32) && (kwv >= 0) && (kwv < 64);
#pragma unroll
            for (int r = 0; r < 4; r++) {
                const bool valid = kok && ((imask >> (j * 4 + r)) & 1);
                const float s = valid ? a[r] : -3e38f;
                sv[j][r] = s;
                mx4[r] = fmaxf(mx4[r], s);
            }
        }
    }
#pragma unroll
    for (int d = 1; d < 16; d <<= 1)
#pragma unroll
        for (int r = 0; r < 4; r++) mx4[r] = fmaxf(mx4[r], __shfl_xor(mx4[r], d));
    if (n16 == 0) {
#pragma unroll
        for (int r = 0; r < 4; r++) mxbuf[w * 16 + quad * 4 + r] = mx4[r];
    }
    __syncthreads();
#pragma unroll
    for (int r = 0; r < 4; r++) mx4[r] = fmaxf(mx4[r], mxbuf[(w ^ 1) * 16 + quad * 4 + r]);

    float sum4[4] = {0.f, 0.f, 0.f, 0.f};
#pragma unroll
    for (int j = 0; j < 10; j++) {
        const int slot = (nth * 10 + j) * 16 + n16;
#pragma unroll
        for (int r = 0; r < 4; r++) {
            const float p = __expf(sv[j][r] - mx4[r]);
            const ushort ph = f2h(p);
            sum4[r] += h2f(ph);
            P[(16 * mt + quad * 4 + r) * 328 + slot] = ph;
        }
    }
#pragma unroll
    for (int d = 1; d < 16; d <<= 1)
#pragma unroll
        for (int r = 0; r < 4; r++) sum4[r] += __shfl_xor(sum4[r], d);
    if (n16 == 0) {
#pragma unroll
        for (int r = 0; r < 4; r++) sumbuf[w * 16 + quad * 4 + r] = sum4[r];
    }
    __syncthreads();

    // ---- PV: VT gathers hoisted in batches of 5 ----
    const int mtP = w >> 1, ntP = w & 1;
    const int dcol = 16 * ntP + n16;
    const ushort* VTb = VTh + (size_t)bh * 66560;    // 32*2080
    f32x4 acc = f32x4{0, 0, 0, 0};
#pragma unroll
    for (int half = 0; half < 2; half++) {
        f16x8 vf[5], pa[5];
#pragma unroll
        for (int kk = 0; kk < 5; kk++) {
            const int ks = half * 5 + kk;
            const int kh_cl = min(max(qh0 - 3 + ks, 0), 31);
            vf[kk] = *(const f16x8*)&VTb[(size_t)dcol * 2080 + 8 + (kh_cl << 6) + kw0a + quad * 8];
            pa[kk] = *(const f16x8*)&P[(16 * mtP + n16) * 328 + ks * 32 + quad * 8];
        }
#pragma unroll
        for (int kk = 0; kk < 5; kk++) {
            acc = __builtin_amdgcn_mfma_f32_16x16x32_f16(pa[kk], vf[kk], acc, 0, 0, 0);
        }
    }
    if (dcol < 24) {
#pragma unroll
        for (int r = 0; r < 4; r++) {
            const int m = 16 * mtP + quad * 4 + r;
            const float tot = sumbuf[(2 * mtP) * 16 + (m & 15)] +
                              sumbuf[(2 * mtP + 1) * 16 + (m & 15)];
            const float rt = __builtin_amdgcn_rcpf(tot);
            Os[m * 28 + dcol] = f2h(acc[r] * rt);
        }
    }
    __syncthreads();

    // ---- coalesced output: 32 tokens x 24 dims ----
    if (t < 192) {
        const int tok = t / 6, g = t - (t / 6) * 6;
        const ushort4 v = *(const ushort4*)&Os[tok * 28 + g * 4];
        const int tq = ((qh0 + (tok >> 3)) << 6) + qw0 + (tok & 7);
        *(ushort4*)&aws[((size_t)(b * 2048 + tq)) * 192 + head * 24 + g * 4] = v;
    }
}

// ---------------------------------------------------------------------------
// Proj GEMM (fp16 MFMA), inline W cast (R2-verified structure: 128-thr
// blocks, 32 rows each, grid 256x3). out = aws @ Wp^T + bias (fp32 out).
// ---------------------------------------------------------------------------
__global__ __launch_bounds__(128, 4) void gemm_proj(const ushort* __restrict__ Ah,
                                                    const float* __restrict__ Wf,
                                                    const float* __restrict__ bias,
                                                    float* __restrict__ C) {
    __shared__ ushort Ws[64 * 200];

    const int t    = threadIdx.x;
    const int wave = t >> 6, lane = t & 63;
    const int m0   = blockIdx.x * 32 + wave * 16;
    const int j0   = blockIdx.y * 64;
    const int n16  = lane & 15;
    const int kq   = lane >> 4;

    for (int i = t; i < 1536; i += 128) {
        const int r = i / 24, c = i - (i / 24) * 24;
        const float* wsrc = &Wf[(size_t)(j0 + r) * 192 + c * 8];
        const float4 w0 = ld4(wsrc), w1 = ld4(wsrc + 4);
        *(ushort4*)&Ws[r * 200 + c * 8] =
            make_ushort4(f2h(w0.x), f2h(w0.y), f2h(w0.z), f2h(w0.w));
        *(ushort4*)&Ws[r * 200 + c * 8 + 4] =
            make_ushort4(f2h(w1.x), f2h(w1.y), f2h(w1.z), f2h(w1.w));
    }

    const ushort* ap = Ah + (size_t)(m0 + n16) * 192 + kq * 8;

    f16x8 af[6];
#pragma unroll
    for (int ks = 0; ks < 6; ks++) af[ks] = *(const f16x8*)(ap + ks * 32);

    f32x4 acc[4] = {f32x4{0,0,0,0}, f32x4{0,0,0,0}, f32x4{0,0,0,0}, f32x4{0,0,0,0}};

    __syncthreads();

#pragma unroll
    for (int ks = 0; ks < 6; ks++) {
#pragma unroll
        for (int nt = 0; nt < 4; nt++) {
            const f16x8 bf = *(const f16x8*)&Ws[(nt * 16 + n16) * 200 + kq * 8 + ks * 32];
            acc[nt] = __builtin_amdgcn_mfma_f32_16x16x32_f16(af[ks], bf, acc[nt], 0, 0, 0);
        }
    }

#pragma unroll
    for (int nt = 0; nt < 4; nt++) {
        const int col = j0 + nt * 16 + n16;
        const float bv = bias[col];
#pragma unroll
        for (int r = 0; r < 4; r++) {
            const int m = m0 + kq * 4 + r;
            C[(size_t)m * 192 + col] = acc[nt][r] + bv;
        }
    }
}

// ---------------------------------------------------------------------------
// Launch: gemm_qkv (128,9) -> attn_mfma (2048) -> gemm_proj (256,3)
// ---------------------------------------------------------------------------
extern "C" void kernel_launch(void* const* d_in, const int* in_sizes, int n_in,
                              void* d_out, int out_size, void* d_ws, size_t ws_size,
                              hipStream_t stream) {
    const float* x      = (const float*)d_in[0];
    const float* qkv_w  = (const float*)d_in[1];
    const float* qkv_b  = (const float*)d_in[2];
    const float* proj_w = (const float*)d_in[3];
    const float* proj_b = (const float*)d_in[4];
    // d_in[5] mask: fixed 7x11 window, recomputed analytically; unused.

    char* wsb = (char*)d_ws;
    ushort* Qh   = (ushort*)(wsb + 0);          // [32,2048,32] fp16
    ushort* Kh   = (ushort*)(wsb + 4194304);    // [32,2048,32]
    ushort* VTh  = (ushort*)(wsb + 8388608);    // [32,32,2080]
    ushort* awsh = (ushort*)(wsb + 12648448);   // [8192,192]
    float*  out  = (float*)d_out;

    hipLaunchKernelGGL(gemm_qkv, dim3(128, 9), dim3(256), 0, stream,
                       x, qkv_w, qkv_b, Qh, Kh, VTh);
    hipLaunchKernelGGL(attn_mfma, dim3(2048), dim3(256), 0, stream,
                       Qh, Kh, VTh, awsh);
    hipLaunchKernelGGL(gemm_proj, dim3(256, 3), dim3(128), 0, stream,
                       awsh, proj_w, proj_b, out);
}